// Round 3
// baseline (158.731 us; speedup 1.0000x reference)
//
#include <hip/hip_runtime.h>

// Problem constants
#define NN 20000
#define SS 400
#define QQ 20
#define PP 3
#define QP (QQ*PP)          // 60 floats per row
#define NPB 64              // n per block (one per lane)
#define NBLK ((NN + NPB - 1)/NPB)   // 313
#define NPAD (NBLK*NPB)     // 20032

#define GSPLIT 5            // s-pair chunks across gridDim.y
#define SPAIRS (SS/2)       // 200 s-pairs
#define SP_PER_BLK (SPAIRS/GSPLIT)  // 40
#define WAVES 4
#define BLK_B (WAVES*64)    // 256
#define SP_PER_WAVE (SP_PER_BLK/WAVES)  // 10

// ws layout (floats):
#define WS_H    0                      // interleaved heads2 pairs: [200][60][2]
#define WS_R    (SPAIRS*QP*2)          // 24000: ratios2 [400] (pair layout == contiguous)
#define WS_COV  (WS_R + SS)            // 24400: partial coverage [GSPLIT][NPAD]
#define WS_PART (WS_COV + GSPLIT*NPAD) // per-block term partials
#define CBLK    ((NPAD + 255)/256)     // 79 combine blocks

typedef float v2f __attribute__((ext_vector_type(2)));

__device__ __forceinline__ v2f lo4(float4 f) { v2f r; r.x = f.x; r.y = f.y; return r; }
__device__ __forceinline__ v2f hi4(float4 f) { v2f r; r.x = f.z; r.y = f.w; return r; }

__global__ void prep_kernel(const float* __restrict__ heads_param,
                            const float* __restrict__ ratios_param,
                            float* __restrict__ out, float* __restrict__ ws) {
    int i = blockIdx.x * blockDim.x + threadIdx.x;
    if (i < SS*QP) {
        float v = heads_param[i];
        float v2 = v * v;
        out[1 + SS + i] = v2;                    // heads output section
        int s = i / QP;
        int k = i - s * QP;
        int sp = s >> 1, j = s & 1;
        ws[WS_H + (sp*QP + k)*2 + j] = v2;       // s-pair interleaved table
    }
    if (i < SS) {
        float v = ratios_param[i];
        float v2 = v * v;
        out[1 + i] = v2;                         // ratios output section
        ws[WS_R + i] = v2;                       // pair layout == contiguous
    }
}

// One chunk = 4 q-dots (12 pauli floats = 3 named float4s PA,PB,PC;
// 6 float4 LDS reads of the interleaved s-pair heads row).
#define DOT_CHUNK(c, PA, PB, PC)                                        \
    do {                                                                \
        float4 f0 = row4[(c)*6+0];                                      \
        float4 f1 = row4[(c)*6+1];                                      \
        float4 f2 = row4[(c)*6+2];                                      \
        float4 f3 = row4[(c)*6+3];                                      \
        float4 f4 = row4[(c)*6+4];                                      \
        float4 f5 = row4[(c)*6+5];                                      \
        v2f d0 = lo4(f0)*PA.x + hi4(f0)*PA.y + lo4(f1)*PA.z;            \
        v2f d1 = hi4(f1)*PA.w + lo4(f2)*PB.x + hi4(f2)*PB.y;            \
        v2f d2 = lo4(f3)*PB.z + hi4(f3)*PB.w + lo4(f4)*PC.x;            \
        v2f d3 = hi4(f4)*PC.y + lo4(f5)*PC.z + hi4(f5)*PC.w;            \
        pa *= d0 * d1;                                                  \
        pb *= d2 * d3;                                                  \
    } while (0)

__global__ __launch_bounds__(BLK_B, 4) void main_kernel(
        const float* __restrict__ pauli, float* __restrict__ ws) {
    __shared__ float4 lds_h4[SP_PER_BLK * QP / 2];   // 40*30 = 1200 float4 = 19.2 KB
    __shared__ float4 lds_r4[SP_PER_BLK / 2];        // 20 float4 (40 v2f pairs)
    __shared__ float  lds_cov[WAVES][NPB];

    const int tid  = threadIdx.x;
    const int wave = __builtin_amdgcn_readfirstlane(tid >> 6);
    const int lane = tid & 63;
    const int g    = blockIdx.y;
    const int n    = blockIdx.x * NPB + lane;
    const int nc   = (n < NN) ? n : (NN - 1);

    // Cooperative stage of this block's heads2 s-pair chunk + ratio pairs
    {
        const float4* srcH = reinterpret_cast<const float4*>(ws + WS_H + (size_t)g * (SP_PER_BLK*QP*2));
        for (int i = tid; i < SP_PER_BLK*QP/2; i += BLK_B) lds_h4[i] = srcH[i];
        const float4* srcR = reinterpret_cast<const float4*>(ws + WS_R + g * (SP_PER_BLK*2));
        if (tid < SP_PER_BLK/2) lds_r4[tid] = srcR[tid];
    }

    // This lane's pauli row: 60 floats in 15 NAMED float4 registers (no array
    // -> no scratch spill; round-2's 107 MB WRITE_SIZE was pl[60] in local mem)
    const float4* p4 = reinterpret_cast<const float4*>(pauli + (size_t)nc * QP);
    float4 p0  = p4[0],  p1  = p4[1],  p2  = p4[2],  p3  = p4[3],  p4v = p4[4];
    float4 p5  = p4[5],  p6  = p4[6],  p7  = p4[7],  p8  = p4[8],  p9  = p4[9];
    float4 p10 = p4[10], p11 = p4[11], p12 = p4[12], p13 = p4[13], p14 = p4[14];

    __syncthreads();

    const v2f* r2p = reinterpret_cast<const v2f*>(lds_r4);

    v2f cov2; cov2.x = 0.f; cov2.y = 0.f;
    #pragma unroll 2
    for (int i = 0; i < SP_PER_WAVE; ++i) {
        const int spl = wave * SP_PER_WAVE + i;
        const float4* row4 = lds_h4 + spl * (QP*2/4);   // 30 float4 per s-pair row
        v2f pa; pa.x = 1.f; pa.y = 1.f;
        v2f pb; pb.x = 1.f; pb.y = 1.f;
        DOT_CHUNK(0, p0,  p1,  p2);
        DOT_CHUNK(1, p3,  p4v, p5);
        DOT_CHUNK(2, p6,  p7,  p8);
        DOT_CHUNK(3, p9,  p10, p11);
        DOT_CHUNK(4, p12, p13, p14);
        cov2 += r2p[spl] * (pa * pb);
    }

    lds_cov[wave][lane] = cov2.x + cov2.y;
    __syncthreads();

    if (tid < NPB) {
        float c = 0.f;
        #pragma unroll
        for (int w = 0; w < WAVES; ++w) c += lds_cov[w][tid];
        ws[WS_COV + (size_t)g * NPAD + blockIdx.x * NPB + tid] = c;
    }
}

__global__ void combine_kernel(const float* __restrict__ wsc,
                               const float* __restrict__ coeff,
                               float* __restrict__ ws) {
    __shared__ float red[4];
    const int tid = threadIdx.x;
    const int n = blockIdx.x * 256 + tid;
    float term = 0.f;
    if (n < NN) {
        float cov = 0.f;
        #pragma unroll
        for (int g = 0; g < GSPLIT; ++g) cov += wsc[WS_COV + (size_t)g * NPAD + n];
        float c = coeff[n];
        term = (c * c) / cov;
    }
    #pragma unroll
    for (int off = 32; off; off >>= 1) term += __shfl_down(term, off);
    if ((tid & 63) == 0) red[tid >> 6] = term;
    __syncthreads();
    if (tid == 0) ws[WS_PART + blockIdx.x] = red[0] + red[1] + red[2] + red[3];
}

__global__ void final_kernel(const float* __restrict__ ws, float* __restrict__ out) {
    int tid = threadIdx.x;  // 128 threads
    double acc = 0.0;
    for (int i = tid; i < CBLK; i += 128) acc += (double)ws[WS_PART + i];
    #pragma unroll
    for (int off = 32; off; off >>= 1) acc += __shfl_down(acc, off);
    __shared__ double r2[2];
    if ((tid & 63) == 0) r2[tid >> 6] = acc;
    __syncthreads();
    if (tid == 0) out[0] = (float)(r2[0] + r2[1]);
}

extern "C" void kernel_launch(void* const* d_in, const int* in_sizes, int n_in,
                              void* d_out, int out_size, void* d_ws, size_t ws_size,
                              hipStream_t stream) {
    const float* heads_param  = (const float*)d_in[0];   // [S,Q,P]
    const float* ratios_param = (const float*)d_in[1];   // [S]
    const float* pauli        = (const float*)d_in[2];   // [N,Q,P]
    const float* coeff        = (const float*)d_in[3];   // [N]
    float* out = (float*)d_out;
    float* ws  = (float*)d_ws;

    prep_kernel<<<(SS*QP + 255)/256, 256, 0, stream>>>(heads_param, ratios_param, out, ws);
    main_kernel<<<dim3(NBLK, GSPLIT), BLK_B, 0, stream>>>(pauli, ws);
    combine_kernel<<<CBLK, 256, 0, stream>>>(ws, coeff, ws);
    final_kernel<<<1, 128, 0, stream>>>(ws, out);
}

// Round 4
// 84.884 us; speedup vs baseline: 1.8700x; 1.8700x over previous
//
#include <hip/hip_runtime.h>

// Problem constants
#define NN 20000
#define SS 400
#define QQ 20
#define PP 3
#define QP (QQ*PP)          // 60 floats per row
#define NPB 64              // n per block (one per lane)
#define NBLK ((NN + NPB - 1)/NPB)   // 313
#define NPAD (NBLK*NPB)     // 20032

#define GSPLIT 5            // s-pair chunks across gridDim.y
#define SPAIRS (SS/2)       // 200 s-pairs
#define SP_PER_BLK (SPAIRS/GSPLIT)  // 40
#define WAVES 4
#define BLK_B (WAVES*64)    // 256
#define SP_PER_WAVE (SP_PER_BLK/WAVES)  // 10

// ws layout (floats):
#define WS_H    0                      // interleaved heads2 pairs: [200][60][2]
#define WS_R    (SPAIRS*QP*2)          // 24000: ratios2 [400] (pair layout == contiguous)
#define WS_COV  (WS_R + SS)            // 24400: partial coverage [GSPLIT][NPAD]
#define WS_PART (WS_COV + GSPLIT*NPAD) // per-block term partials
#define CBLK    ((NPAD + 255)/256)     // 79 combine blocks

typedef float v2f __attribute__((ext_vector_type(2)));

__device__ __forceinline__ v2f lo4(float4 f) { v2f r; r.x = f.x; r.y = f.y; return r; }
__device__ __forceinline__ v2f hi4(float4 f) { v2f r; r.x = f.z; r.y = f.w; return r; }

__global__ void prep_kernel(const float* __restrict__ heads_param,
                            const float* __restrict__ ratios_param,
                            float* __restrict__ out, float* __restrict__ ws) {
    int i = blockIdx.x * blockDim.x + threadIdx.x;
    if (i < SS*QP) {
        float v = heads_param[i];
        float v2 = v * v;
        out[1 + SS + i] = v2;                    // heads output section
        int s = i / QP;
        int k = i - s * QP;
        int sp = s >> 1, j = s & 1;
        ws[WS_H + (sp*QP + k)*2 + j] = v2;       // s-pair interleaved table
    }
    if (i < SS) {
        float v = ratios_param[i];
        float v2 = v * v;
        out[1 + i] = v2;                         // ratios output section
        ws[WS_R + i] = v2;                       // pair layout == contiguous
    }
}

// One chunk = 4 q-dots (12 pauli floats = 3 named float4s PA,PB,PC;
// 6 float4 LDS reads of the interleaved s-pair heads row).
#define DOT_CHUNK(c, PA, PB, PC)                                        \
    do {                                                                \
        float4 f0 = row4[(c)*6+0];                                      \
        float4 f1 = row4[(c)*6+1];                                      \
        float4 f2 = row4[(c)*6+2];                                      \
        float4 f3 = row4[(c)*6+3];                                      \
        float4 f4 = row4[(c)*6+4];                                      \
        float4 f5 = row4[(c)*6+5];                                      \
        v2f d0 = lo4(f0)*PA.x + hi4(f0)*PA.y + lo4(f1)*PA.z;            \
        v2f d1 = hi4(f1)*PA.w + lo4(f2)*PB.x + hi4(f2)*PB.y;            \
        v2f d2 = lo4(f3)*PB.z + hi4(f3)*PB.w + lo4(f4)*PC.x;            \
        v2f d3 = hi4(f4)*PC.y + lo4(f5)*PC.z + hi4(f5)*PC.w;            \
        pa *= d0 * d1;                                                  \
        pb *= d2 * d3;                                                  \
    } while (0)

__global__ __launch_bounds__(BLK_B)
__attribute__((amdgpu_waves_per_eu(4, 4)))   // pin occupancy window: allocator may
                                             // use up to 128 VGPRs (r2/r3: 64-VGPR
                                             // heuristic caused spill/remat, 230MB FETCH)
void main_kernel(const float* __restrict__ pauli, float* __restrict__ ws) {
    __shared__ float4 lds_h4[SP_PER_BLK * QP / 2];   // 40*30 = 1200 float4 = 19.2 KB
    __shared__ float4 lds_r4[SP_PER_BLK / 2];        // 20 float4 (40 v2f pairs)
    __shared__ float  lds_cov[WAVES][NPB];

    const int tid  = threadIdx.x;
    const int wave = __builtin_amdgcn_readfirstlane(tid >> 6);
    const int lane = tid & 63;
    const int g    = blockIdx.y;
    const int n    = blockIdx.x * NPB + lane;
    const int nc   = (n < NN) ? n : (NN - 1);

    // Cooperative stage of this block's heads2 s-pair chunk + ratio pairs
    {
        const float4* srcH = reinterpret_cast<const float4*>(ws + WS_H + (size_t)g * (SP_PER_BLK*QP*2));
        for (int i = tid; i < SP_PER_BLK*QP/2; i += BLK_B) lds_h4[i] = srcH[i];
        const float4* srcR = reinterpret_cast<const float4*>(ws + WS_R + g * (SP_PER_BLK*2));
        if (tid < SP_PER_BLK/2) lds_r4[tid] = srcR[tid];
    }

    // This lane's pauli row: 60 floats in 15 NAMED float4 registers
    const float4* p4 = reinterpret_cast<const float4*>(pauli + (size_t)nc * QP);
    float4 p0  = p4[0],  p1  = p4[1],  p2  = p4[2],  p3  = p4[3],  p4v = p4[4];
    float4 p5  = p4[5],  p6  = p4[6],  p7  = p4[7],  p8  = p4[8],  p9  = p4[9];
    float4 p10 = p4[10], p11 = p4[11], p12 = p4[12], p13 = p4[13], p14 = p4[14];

    __syncthreads();

    const v2f* r2p = reinterpret_cast<const v2f*>(lds_r4);

    v2f cov2; cov2.x = 0.f; cov2.y = 0.f;
    #pragma unroll 1
    for (int i = 0; i < SP_PER_WAVE; ++i) {
        const int spl = wave * SP_PER_WAVE + i;
        const float4* row4 = lds_h4 + spl * (QP*2/4);   // 30 float4 per s-pair row
        v2f pa; pa.x = 1.f; pa.y = 1.f;
        v2f pb; pb.x = 1.f; pb.y = 1.f;
        DOT_CHUNK(0, p0,  p1,  p2);
        DOT_CHUNK(1, p3,  p4v, p5);
        DOT_CHUNK(2, p6,  p7,  p8);
        DOT_CHUNK(3, p9,  p10, p11);
        DOT_CHUNK(4, p12, p13, p14);
        cov2 += r2p[spl] * (pa * pb);
    }

    lds_cov[wave][lane] = cov2.x + cov2.y;
    __syncthreads();

    if (tid < NPB) {
        float c = 0.f;
        #pragma unroll
        for (int w = 0; w < WAVES; ++w) c += lds_cov[w][tid];
        ws[WS_COV + (size_t)g * NPAD + blockIdx.x * NPB + tid] = c;
    }
}

__global__ void combine_kernel(const float* __restrict__ wsc,
                               const float* __restrict__ coeff,
                               float* __restrict__ ws) {
    __shared__ float red[4];
    const int tid = threadIdx.x;
    const int n = blockIdx.x * 256 + tid;
    float term = 0.f;
    if (n < NN) {
        float cov = 0.f;
        #pragma unroll
        for (int g = 0; g < GSPLIT; ++g) cov += wsc[WS_COV + (size_t)g * NPAD + n];
        float c = coeff[n];
        term = (c * c) / cov;
    }
    #pragma unroll
    for (int off = 32; off; off >>= 1) term += __shfl_down(term, off);
    if ((tid & 63) == 0) red[tid >> 6] = term;
    __syncthreads();
    if (tid == 0) ws[WS_PART + blockIdx.x] = red[0] + red[1] + red[2] + red[3];
}

__global__ void final_kernel(const float* __restrict__ ws, float* __restrict__ out) {
    int tid = threadIdx.x;  // 128 threads
    double acc = 0.0;
    for (int i = tid; i < CBLK; i += 128) acc += (double)ws[WS_PART + i];
    #pragma unroll
    for (int off = 32; off; off >>= 1) acc += __shfl_down(acc, off);
    __shared__ double r2[2];
    if ((tid & 63) == 0) r2[tid >> 6] = acc;
    __syncthreads();
    if (tid == 0) out[0] = (float)(r2[0] + r2[1]);
}

extern "C" void kernel_launch(void* const* d_in, const int* in_sizes, int n_in,
                              void* d_out, int out_size, void* d_ws, size_t ws_size,
                              hipStream_t stream) {
    const float* heads_param  = (const float*)d_in[0];   // [S,Q,P]
    const float* ratios_param = (const float*)d_in[1];   // [S]
    const float* pauli        = (const float*)d_in[2];   // [N,Q,P]
    const float* coeff        = (const float*)d_in[3];   // [N]
    float* out = (float*)d_out;
    float* ws  = (float*)d_ws;

    prep_kernel<<<(SS*QP + 255)/256, 256, 0, stream>>>(heads_param, ratios_param, out, ws);
    main_kernel<<<dim3(NBLK, GSPLIT), BLK_B, 0, stream>>>(pauli, ws);
    combine_kernel<<<CBLK, 256, 0, stream>>>(ws, coeff, ws);
    final_kernel<<<1, 128, 0, stream>>>(ws, out);
}

// Round 5
// 34.822 us; speedup vs baseline: 4.5583x; 2.4377x over previous
//
#include <hip/hip_runtime.h>

// Problem constants
#define NN 20000
#define SS 400
#define QQ 20
#define PP 3
#define QP (QQ*PP)          // 60 floats per row
#define NPB 64              // n per block (one per lane)
#define NBLK ((NN + NPB - 1)/NPB)   // 313
#define NPAD (NBLK*NPB)     // 20032

#define GSPLIT 10           // s-pair chunks across gridDim.y
#define SPAIRS (SS/2)       // 200 s-pairs
#define SP_PER_BLK (SPAIRS/GSPLIT)  // 20
#define WAVES 4
#define BLK_B (WAVES*64)    // 256
#define SP_PER_WAVE (SP_PER_BLK/WAVES)  // 5

// ws layout (floats):
#define WS_H    0                      // interleaved heads2 pairs: [200][60][2]
#define WS_R    (SPAIRS*QP*2)          // 24000: ratios2 [400] (pair layout == contiguous)
#define WS_COV  (WS_R + SS)            // 24400: partial coverage [GSPLIT][NPAD]
#define WS_PART (WS_COV + GSPLIT*NPAD) // per-block term partials
#define CBLK    ((NPAD + 255)/256)     // 79 combine blocks

typedef float v2f __attribute__((ext_vector_type(2)));

__device__ __forceinline__ v2f lo4(float4 f) { v2f r; r.x = f.x; r.y = f.y; return r; }
__device__ __forceinline__ v2f hi4(float4 f) { v2f r; r.x = f.z; r.y = f.w; return r; }

__global__ void prep_kernel(const float* __restrict__ heads_param,
                            const float* __restrict__ ratios_param,
                            float* __restrict__ out, float* __restrict__ ws) {
    int i = blockIdx.x * blockDim.x + threadIdx.x;
    if (i < SS*QP) {
        float v = heads_param[i];
        float v2 = v * v;
        out[1 + SS + i] = v2;                    // heads output section
        int s = i / QP;
        int k = i - s * QP;
        int sp = s >> 1, j = s & 1;
        ws[WS_H + (sp*QP + k)*2 + j] = v2;       // s-pair interleaved table
    }
    if (i < SS) {
        float v = ratios_param[i];
        float v2 = v * v;
        out[1 + i] = v2;                         // ratios output section
        ws[WS_R + i] = v2;                       // pair layout == contiguous
    }
}

// One q-chunk (4 qubits, 12 pauli floats in float4 pqa/pqb/pqc) update of one
// s-pair accumulator. row4 points at this s-pair's chunk (6 float4s, broadcast).
#define SP_STEP(ACC, SP)                                                \
    do {                                                                \
        const float4* row4 = lds_h4 + (wbase + (SP))*30 + c*6;          \
        float4 f0 = row4[0], f1 = row4[1], f2 = row4[2];                \
        v2f d0 = lo4(f0)*pqa.x + hi4(f0)*pqa.y + lo4(f1)*pqa.z;         \
        v2f d1 = hi4(f1)*pqa.w + lo4(f2)*pqb.x + hi4(f2)*pqb.y;         \
        float4 f3 = row4[3], f4 = row4[4], f5 = row4[5];                \
        v2f d2 = lo4(f3)*pqb.z + hi4(f3)*pqb.w + lo4(f4)*pqc.x;         \
        v2f d3 = hi4(f4)*pqc.y + lo4(f5)*pqc.z + hi4(f5)*pqc.w;         \
        ACC *= (d0*d1)*(d2*d3);                                         \
    } while (0)

__global__ __launch_bounds__(BLK_B) void main_kernel(
        const float* __restrict__ pauli, float* __restrict__ ws) {
    __shared__ float4 lds_h4[SP_PER_BLK * QP / 2];   // 20*30 = 600 float4 = 9.6 KB
    __shared__ float4 lds_r4[SP_PER_BLK * 2 / 4];    // 10 float4 (20 v2f pairs)
    __shared__ float  lds_cov[WAVES][NPB];

    const int tid  = threadIdx.x;
    const int wave = __builtin_amdgcn_readfirstlane(tid >> 6);
    const int lane = tid & 63;
    const int g    = blockIdx.y;
    const int n    = blockIdx.x * NPB + lane;
    const int nc   = (n < NN) ? n : (NN - 1);
    const int wbase = wave * SP_PER_WAVE;

    // Cooperative stage of this block's heads2 s-pair chunk + ratio pairs
    {
        const float4* srcH = reinterpret_cast<const float4*>(ws + WS_H + (size_t)g * (SP_PER_BLK*QP*2));
        for (int i = tid; i < SP_PER_BLK*QP/2; i += BLK_B) lds_h4[i] = srcH[i];
        const float4* srcR = reinterpret_cast<const float4*>(ws + WS_R + g * (SP_PER_BLK*2));
        if (tid < SP_PER_BLK*2/4) lds_r4[tid] = srcR[tid];
    }

    const float4* p4 = reinterpret_cast<const float4*>(pauli + (size_t)nc * QP);

    __syncthreads();

    // Per-s-pair partial-product accumulators (NAMED -> registers; q-phase
    // split keeps live set ~56 VGPR so the 64-VGPR budget never spills)
    v2f a0, a1, a2, a3, a4;
    a0.x=1.f; a0.y=1.f; a1=a0; a2=a0; a3=a0; a4=a0;

    #pragma unroll 1       // keep phases serial: only 12 pauli floats live at once
    for (int c = 0; c < 5; ++c) {
        float4 pqa = p4[c*3+0], pqb = p4[c*3+1], pqc = p4[c*3+2];
        SP_STEP(a0, 0);
        SP_STEP(a1, 1);
        SP_STEP(a2, 2);
        SP_STEP(a3, 3);
        SP_STEP(a4, 4);
    }

    const v2f* r2p = reinterpret_cast<const v2f*>(lds_r4);
    v2f cov2 = r2p[wbase+0]*a0 + r2p[wbase+1]*a1 + r2p[wbase+2]*a2
             + r2p[wbase+3]*a3 + r2p[wbase+4]*a4;

    lds_cov[wave][lane] = cov2.x + cov2.y;
    __syncthreads();

    if (tid < NPB) {
        float cv = 0.f;
        #pragma unroll
        for (int w = 0; w < WAVES; ++w) cv += lds_cov[w][tid];
        ws[WS_COV + (size_t)g * NPAD + blockIdx.x * NPB + tid] = cv;
    }
}

__global__ void combine_kernel(const float* __restrict__ wsc,
                               const float* __restrict__ coeff,
                               float* __restrict__ ws) {
    __shared__ float red[4];
    const int tid = threadIdx.x;
    const int n = blockIdx.x * 256 + tid;
    float term = 0.f;
    if (n < NN) {
        float cov = 0.f;
        #pragma unroll
        for (int g = 0; g < GSPLIT; ++g) cov += wsc[WS_COV + (size_t)g * NPAD + n];
        float c = coeff[n];
        term = (c * c) / cov;
    }
    #pragma unroll
    for (int off = 32; off; off >>= 1) term += __shfl_down(term, off);
    if ((tid & 63) == 0) red[tid >> 6] = term;
    __syncthreads();
    if (tid == 0) ws[WS_PART + blockIdx.x] = red[0] + red[1] + red[2] + red[3];
}

__global__ void final_kernel(const float* __restrict__ ws, float* __restrict__ out) {
    int tid = threadIdx.x;  // 128 threads
    double acc = 0.0;
    for (int i = tid; i < CBLK; i += 128) acc += (double)ws[WS_PART + i];
    #pragma unroll
    for (int off = 32; off; off >>= 1) acc += __shfl_down(acc, off);
    __shared__ double r2[2];
    if ((tid & 63) == 0) r2[tid >> 6] = acc;
    __syncthreads();
    if (tid == 0) out[0] = (float)(r2[0] + r2[1]);
}

extern "C" void kernel_launch(void* const* d_in, const int* in_sizes, int n_in,
                              void* d_out, int out_size, void* d_ws, size_t ws_size,
                              hipStream_t stream) {
    const float* heads_param  = (const float*)d_in[0];   // [S,Q,P]
    const float* ratios_param = (const float*)d_in[1];   // [S]
    const float* pauli        = (const float*)d_in[2];   // [N,Q,P]
    const float* coeff        = (const float*)d_in[3];   // [N]
    float* out = (float*)d_out;
    float* ws  = (float*)d_ws;

    prep_kernel<<<(SS*QP + 255)/256, 256, 0, stream>>>(heads_param, ratios_param, out, ws);
    main_kernel<<<dim3(NBLK, GSPLIT), BLK_B, 0, stream>>>(pauli, ws);
    combine_kernel<<<CBLK, 256, 0, stream>>>(ws, coeff, ws);
    final_kernel<<<1, 128, 0, stream>>>(ws, out);
}